// Round 6
// baseline (501.681 us; speedup 1.0000x reference)
//
#include <hip/hip_runtime.h>
#include <hip/hip_bf16.h>

typedef unsigned short u16;
typedef __attribute__((ext_vector_type(8))) short short8;
typedef __attribute__((ext_vector_type(4))) short short4v;
typedef __attribute__((ext_vector_type(4))) float f32x4;

#define NN 50000
#define EE 400000
#define GG 256
#define MP 50048      // 391 * 128 padded rows
#define KS 64         // gemm1 K: 23 node_s + 16 vnorm + 1 ones + 24 zero
#define K2 320        // gemm2 K: 40 + 256 meanH + 24 zero
#define EWS 260       // u16 stride for EW LDS rows (conflict-free scatter)
#define NG (EE / 16)  // 25000 global 16-edge groups
#define ZB 12500      // zero-blocks for XL2acc in phase1

static __device__ __forceinline__ __hip_bfloat16 f2b(float x) { return __float2bfloat16(x); }
static __device__ __forceinline__ float u16tof(u16 v) {
    unsigned x = ((unsigned)v) << 16;
    float f;
    __builtin_memcpy(&f, &x, 4);
    return f;
}
static __device__ __forceinline__ u16 ftou16(float x) {
    __hip_bfloat16 h = __float2bfloat16(x);
    u16 b;
    __builtin_memcpy(&b, &h, 2);
    return b;
}

// uniform row a[j] (scalar loads) dotted with column b[j*256+c] (coalesced).
static __device__ __forceinline__ float dot256(const float* __restrict__ a,
                                               const float* __restrict__ b, int c) {
    const float* __restrict__ bp = b + c;
    float s0 = 0.f, s1 = 0.f, s2 = 0.f, s3 = 0.f;
    float s4 = 0.f, s5 = 0.f, s6 = 0.f, s7 = 0.f;
#pragma unroll 4
    for (int j = 0; j < 256; j += 8) {
        s0 += a[j]     * bp[(size_t)(j)     * 256];
        s1 += a[j + 1] * bp[(size_t)(j + 1) * 256];
        s2 += a[j + 2] * bp[(size_t)(j + 2) * 256];
        s3 += a[j + 3] * bp[(size_t)(j + 3) * 256];
        s4 += a[j + 4] * bp[(size_t)(j + 4) * 256];
        s5 += a[j + 5] * bp[(size_t)(j + 5) * 256];
        s6 += a[j + 6] * bp[(size_t)(j + 6) * 256];
        s7 += a[j + 7] * bp[(size_t)(j + 7) * 256];
    }
    return ((s0 + s1) + (s2 + s3)) + ((s4 + s5) + (s6 + s7));
}

// ================= phase1: weight packing + embed-lite + degree counts + batch boundaries ======
// [0,64) W1pqT | [64,384) W2T | [384,403) Wc/bc/crow | [403,12903) embed | [12903,14466) deg
// [14466,14662) batch bounds | [14662,14662+ZB) zero XL2acc
__global__ __launch_bounds__(256) void phase1(const float* __restrict__ Wm1,
                                              const float* __restrict__ Wn,
                                              const float* __restrict__ Wm2,
                                              const float* __restrict__ We,
                                              const float* __restrict__ be,
                                              const float* __restrict__ bm1,
                                              const float* __restrict__ bm2,
                                              const float* __restrict__ Ws,
                                              const float* __restrict__ bs,
                                              __hip_bfloat16* __restrict__ W1pqT,
                                              __hip_bfloat16* __restrict__ W2T,
                                              float* __restrict__ Wc, float* __restrict__ bc,
                                              float* __restrict__ crow,
                                              const float* __restrict__ node_s,
                                              const float* __restrict__ node_v,
                                              const float* __restrict__ Wv,
                                              const float* __restrict__ bv,
                                              __hip_bfloat16* __restrict__ XL2,
                                              const int* __restrict__ ei,
                                              const int* __restrict__ batch,
                                              int* __restrict__ cnt,
                                              int* __restrict__ gstart,
                                              float* __restrict__ XL2acc) {
    int blk = blockIdx.x, tid = threadIdx.x;
    if (blk < 64) {
        int k = blk;
#pragma unroll
        for (int half = 0; half < 2; ++half) {
            int c = half * 256 + tid;
            int cc = c & 255;
            const float* Wm1h = (c < 256) ? Wm1 : (Wm1 + 256 * 256);
            float v = 0.f;
            if (k < 23) v = dot256(&Ws[k * 256], Wm1h, cc);
            else if (k < 39) { if (c >= 256) v = Wm1[(512 + (k - 23)) * 256 + cc]; }
            else if (k == 39) v = dot256(bs, Wm1h, cc);
            W1pqT[c * KS + k] = f2b(v);
        }
    } else if (blk < 384) {
        int k = blk - 64, c = tid;
        float v = 0.f;
        if (k < 23) v = dot256(&Ws[k * 256], Wn, c);
        else if (k < 39) v = Wn[(256 + (k - 23)) * 256 + c];
        else if (k == 39) v = dot256(bs, Wn, c);
        else if (k < 296) v = dot256(&Wm2[(k - 40) * 256], Wn, c);
        W2T[c * K2 + k] = f2b(v);
    } else if (blk < 403) {
        int b = blk - 384, c = tid;
        if (b < 17) Wc[b * 256 + c] = dot256(&We[b * 256], &Wm1[528 * 256], c);
        else if (b == 17) bc[c] = bm1[c] + dot256(be, &Wm1[528 * 256], c);
        else crow[c] = dot256(bm2, Wn, c);
    } else if (blk < 12903) {
        int w = tid >> 6, lane = tid & 63;
        int n = (blk - 403) * 4 + w;
        if (n < NN) {
            float lv = (lane < 23) ? node_s[(size_t)n * 23 + lane] : 0.f;
            float vv = (lane < 12) ? node_v[(size_t)n * 12 + lane] : 0.f;
            float nvk[12];
#pragma unroll
            for (int k = 0; k < 12; ++k) nvk[k] = __shfl(vv, k, 64);
            float vn = 0.f;
            if (lane < 16) {
                float b0 = bv[lane];
                float vx = b0, vy = b0, vz = b0;
#pragma unroll
                for (int k = 0; k < 4; ++k) {
                    float wv = Wv[k * 16 + lane];
                    vx += nvk[k * 3 + 0] * wv;
                    vy += nvk[k * 3 + 1] * wv;
                    vz += nvk[k * 3 + 2] * wv;
                }
                vn = sqrtf(vx * vx + vy * vy + vz * vz);
            }
            int vsrc = (lane >= 23 && lane < 39) ? (lane - 23) : 0;
            float vbc = __shfl(vn, vsrc, 64);
            float outv;
            if (lane < 23) outv = lv;
            else if (lane < 39) outv = vbc;
            else if (lane == 39) outv = 1.f;
            else outv = 0.f;
            __hip_bfloat16* row = XL2 + (size_t)n * K2;
            row[lane] = f2b(outv);
            if (lane < 24) row[296 + lane] = f2b(0.f);
        }
    } else if (blk < 14466) {
        int e = (blk - 12903) * 256 + tid;
        if (e < EE) atomicAdd(&cnt[ei[EE + e]], 1);
    } else if (blk < 14662) {
        // sorted batch -> gstart[g] = lower_bound(g); covers g in [0,GG] exactly once.
        int n = (blk - 14466) * 256 + tid;
        if (n < NN) {
            int bn = batch[n];
            int bp = (n == 0) ? -1 : batch[n - 1];
            for (int g = bp + 1; g <= bn; ++g) gstart[g] = n;
            if (n == NN - 1)
                for (int g = bn + 1; g <= GG; ++g) gstart[g] = NN;
        }
    } else {
        // zero XL2acc: ZB blocks x 256 threads x f32x4 = 12.8M floats exactly
        size_t idx = ((size_t)(blk - 14662) * 256 + tid) * 4;
        f32x4 z = {0.f, 0.f, 0.f, 0.f};
        *(f32x4*)&XL2acc[idx] = z;
    }
}

// ================= CSR build =================
__global__ __launch_bounds__(256) void scan1(const int* __restrict__ cnt, int* __restrict__ rowptr,
                                             int* __restrict__ bsum) {
    int tid = threadIdx.x, i = blockIdx.x * 256 + tid;
    __shared__ int sd[256];
    int v = (i < NN) ? cnt[i] : 0;
    sd[tid] = v;
    __syncthreads();
    for (int off = 1; off < 256; off <<= 1) {
        int t = (tid >= off) ? sd[tid - off] : 0;
        __syncthreads();
        sd[tid] += t;
        __syncthreads();
    }
    if (i < NN) rowptr[i] = sd[tid] - v;
    if (tid == 255) bsum[blockIdx.x] = sd[255];
}
__global__ __launch_bounds__(256) void scan2(int* __restrict__ bsum, const int* __restrict__ gstart,
                                             float* __restrict__ ginv) {
    int c = threadIdx.x;
    __shared__ int sd[256];
    int v = (c < 196) ? bsum[c] : 0;
    sd[c] = v;
    __syncthreads();
    for (int off = 1; off < 256; off <<= 1) {
        int t = (c >= off) ? sd[c - off] : 0;
        __syncthreads();
        sd[c] += t;
        __syncthreads();
    }
    if (c < 196) bsum[c] = sd[c] - v;
    ginv[c] = 1.f / fmaxf((float)(gstart[c + 1] - gstart[c]), 1.f);
}
__global__ __launch_bounds__(256) void scan3(const int* __restrict__ cnt, const int* __restrict__ bsum,
                                             int* __restrict__ rowptr, int* __restrict__ cursor) {
    int i = blockIdx.x * 256 + threadIdx.x;
    if (i < NN) {
        int v = rowptr[i] + bsum[blockIdx.x];
        rowptr[i] = v;
        cursor[i] = v;
        if (i == NN - 1) rowptr[NN] = v + cnt[i];
    }
}

// ================= gemm1 + fill_csr + WcBf pack, fused (independent jobs) =================
__global__ __launch_bounds__(256, 2) void gemm1_fill(const u16* __restrict__ A, const u16* __restrict__ Bt,
                                                     __hip_bfloat16* __restrict__ C,
                                                     const int* __restrict__ ei, int* __restrict__ cursor,
                                                     int* __restrict__ eid,
                                                     const float* __restrict__ Wc,
                                                     u16* __restrict__ WcBf) {
    __shared__ __align__(16) u16 At[128 * 64];
    __shared__ __align__(16) u16 Bs[128 * 64];
    int blk = blockIdx.x, tid = threadIdx.x;
    if (blk >= 1564) {
        if (blk == 3127) {
            // WcBf[ni*512 + l*8 + j] = bf16(Wc[k][ni*16 + (l&15)]), k=(l>>4)*8+j, 0 if k>=17
            for (int idx = tid; idx < 8192; idx += 256) {
                int ni = idx >> 9;
                int l = (idx >> 3) & 63;
                int j = idx & 7;
                int k = ((l >> 4) << 3) + j;
                int c = ni * 16 + (l & 15);
                float v = (k < 17) ? Wc[k * 256 + c] : 0.f;
                WcBf[idx] = ftou16(v);
            }
            return;
        }
        int e = (blk - 1564) * 256 + tid;
        if (e < EE) {
            int d = ei[EE + e];
            int pos = atomicAdd(&cursor[d], 1);
            eid[pos] = e;
        }
        return;
    }
    long m0 = (long)(blk >> 2) * 128;
    long n0 = (long)(blk & 3) * 128;
    int wid = tid >> 6, lane = tid & 63;
    int wm = wid >> 1, wn = wid & 1;
    int quad = lane >> 4, l16 = lane & 15;
    f32x4 acc[4][4] = {};
    int r0 = tid >> 3;
    int cc = (tid & 7) * 8;
    const u16* Ab = A + (m0 + r0) * K2 + cc;
    const u16* Bb = Bt + (n0 + r0) * KS + cc;
#pragma unroll
    for (int i = 0; i < 4; ++i) {
        int row = r0 + i * 32;
        __builtin_amdgcn_global_load_lds(
            (const __attribute__((address_space(1))) void*)(Ab + (long)(i * 32) * K2),
            (__attribute__((address_space(3))) void*)(&At[row * 64 + cc]), 16, 0, 0);
    }
#pragma unroll
    for (int i = 0; i < 4; ++i) {
        int row = r0 + i * 32;
        __builtin_amdgcn_global_load_lds(
            (const __attribute__((address_space(1))) void*)(Bb + (long)(i * 32) * KS),
            (__attribute__((address_space(3))) void*)(&Bs[row * 64 + cc]), 16, 0, 0);
    }
    __syncthreads();
#pragma unroll
    for (int kk = 0; kk < 64; kk += 32) {
        short8 af[4], bf[4];
#pragma unroll
        for (int mi = 0; mi < 4; ++mi)
            af[mi] = *(const short8*)&At[(wm * 64 + mi * 16 + l16) * 64 + kk + quad * 8];
#pragma unroll
        for (int ni = 0; ni < 4; ++ni)
            bf[ni] = *(const short8*)&Bs[(wn * 64 + ni * 16 + l16) * 64 + kk + quad * 8];
#pragma unroll
        for (int mi = 0; mi < 4; ++mi) {
#pragma unroll
            for (int ni = 0; ni < 4; ++ni)
                acc[mi][ni] = __builtin_amdgcn_mfma_f32_16x16x32_bf16(af[mi], bf[ni], acc[mi][ni], 0, 0, 0);
        }
    }
#pragma unroll
    for (int mi = 0; mi < 4; ++mi) {
#pragma unroll
        for (int ni = 0; ni < 4; ++ni) {
            long row = m0 + wm * 64 + mi * 16 + quad * 4;
            long col = n0 + wn * 64 + ni * 16 + l16;
#pragma unroll
            for (int r = 0; r < 4; ++r)
                C[(row + r) * 512 + col] = f2b(acc[mi][ni][r]);
        }
    }
}

// ================= edge aggregation: EDGE-CENTRIC. 1 wave = 1 global 16-edge group ===========
// (CSR-sorted by dst). hidden_e = relu(P[dst]+bc + Q[src] + es[e]@Wc); run-accumulate per dst,
// flush via atomicAdd into XL2acc[dst][256]. Uniform work, no node loop, no spill window.
__global__ __launch_bounds__(256) void edge_agg(const u16* __restrict__ PQ,
                                                const float* __restrict__ edge_s,
                                                const int* __restrict__ ei,
                                                const int* __restrict__ eid,
                                                const u16* __restrict__ WcBf,
                                                const float* __restrict__ bc,
                                                float* __restrict__ XL2acc) {
    __shared__ __align__(16) u16 EWall[4][16 * EWS];
    int tid = threadIdx.x;
    int wv = tid >> 6, lane = tid & 63;
    int G = blockIdx.x * 4 + wv;          // [0, NG) exactly
    u16* __restrict__ EW = &EWall[wv][0];
    int l16 = lane & 15, quad = lane >> 4;
    // group's 16 edges: ids, src, dst (lanes 0..15)
    int e = 0, ssrc = 0, sdst = 0;
    if (lane < 16) {
        e = eid[G * 16 + lane];
        ssrc = ei[e];
        sdst = ei[EE + e];
    }
    // es gather -> A fragment (issued early; overlaps src/dst chain)
    int ev = __shfl(e, l16, 64);
    const float* ep = edge_s + (size_t)ev * 17 + quad * 8;
    float a0 = 0.f, a1 = 0.f, a2 = 0.f, a3 = 0.f, a4 = 0.f, a5 = 0.f, a6 = 0.f, a7 = 0.f;
    if (quad < 2) {
        a0 = ep[0]; a1 = ep[1]; a2 = ep[2]; a3 = ep[3];
        a4 = ep[4]; a5 = ep[5]; a6 = ep[6]; a7 = ep[7];
    } else if (quad == 2) {
        a0 = ep[0];
    }
    f32x4 bc4 = *(const f32x4*)&bc[lane * 4];
#define LQ(jj) (*(const short4v*)&PQ[(size_t)__builtin_amdgcn_readlane(ssrc, (jj)) * 512 + 256 + lane * 4])
#define LP(jj) (*(const short4v*)&PQ[(size_t)__builtin_amdgcn_readlane(sdst, (jj)) * 512 + lane * 4])
    // batch A gathers (edges 0..7) in flight during MFMA block
    short4v qa0 = LQ(0), qa1 = LQ(1), qa2 = LQ(2), qa3 = LQ(3);
    short4v qa4 = LQ(4), qa5 = LQ(5), qa6 = LQ(6), qa7 = LQ(7);
    short4v pa0 = LP(0), pa1 = LP(1), pa2 = LP(2), pa3 = LP(3);
    short4v pa4 = LP(4), pa5 = LP(5), pa6 = LP(6), pa7 = LP(7);
    // A fragment
    short8 af;
    af[0] = (short)ftou16(a0); af[1] = (short)ftou16(a1);
    af[2] = (short)ftou16(a2); af[3] = (short)ftou16(a3);
    af[4] = (short)ftou16(a4); af[5] = (short)ftou16(a5);
    af[6] = (short)ftou16(a6); af[7] = (short)ftou16(a7);
    // 16 MFMA (wcf streamed from L1) + conflict-free LDS scatter
    const f32x4 zf = {0.f, 0.f, 0.f, 0.f};
#pragma unroll
    for (int ni = 0; ni < 16; ++ni) {
        short8 wf = *(const short8*)&WcBf[ni * 512 + lane * 8];
        f32x4 ew = __builtin_amdgcn_mfma_f32_16x16x32_bf16(af, wf, zf, 0, 0, 0);
#pragma unroll
        for (int r = 0; r < 4; ++r)
            EW[(quad * 4 + r) * EWS + ni * 16 + l16] = ftou16(ew[r]);
    }
    // batch B gathers (edges 8..15) in flight during consume of batch A
    short4v qb0 = LQ(8),  qb1 = LQ(9),  qb2 = LQ(10), qb3 = LQ(11);
    short4v qb4 = LQ(12), qb5 = LQ(13), qb6 = LQ(14), qb7 = LQ(15);
    short4v pb0 = LP(8),  pb1 = LP(9),  pb2 = LP(10), pb3 = LP(11);
    short4v pb4 = LP(12), pb5 = LP(13), pb6 = LP(14), pb7 = LP(15);
#undef LQ
#undef LP
    // consume: run-accumulate by dst (wave-uniform), flush on change
    f32x4 racc = {0.f, 0.f, 0.f, 0.f};
    int dcur = __builtin_amdgcn_readlane(sdst, 0);
#define FLUSH                                                                       \
    {                                                                               \
        float* fp = XL2acc + (size_t)dcur * 256 + lane * 4;                         \
        atomicAdd(fp + 0, racc[0]); atomicAdd(fp + 1, racc[1]);                     \
        atomicAdd(fp + 2, racc[2]); atomicAdd(fp + 3, racc[3]);                     \
        racc[0] = 0.f; racc[1] = 0.f; racc[2] = 0.f; racc[3] = 0.f;                 \
    }
#define CONSUME(PP, QQ, c)                                                          \
    {                                                                               \
        int d_ = __builtin_amdgcn_readlane(sdst, (c));                              \
        if (d_ != dcur) { FLUSH; dcur = d_; }                                       \
        short4v ew4 = *(const short4v*)&EW[(c) * EWS + lane * 4];                   \
        _Pragma("unroll")                                                           \
        for (int i = 0; i < 4; ++i)                                                 \
            racc[i] += fmaxf(u16tof((u16)PP[i]) + bc4[i] + u16tof((u16)QQ[i]) +     \
                             u16tof((u16)ew4[i]), 0.f);                             \
    }
    CONSUME(pa0, qa0, 0)  CONSUME(pa1, qa1, 1)  CONSUME(pa2, qa2, 2)  CONSUME(pa3, qa3, 3)
    CONSUME(pa4, qa4, 4)  CONSUME(pa5, qa5, 5)  CONSUME(pa6, qa6, 6)  CONSUME(pa7, qa7, 7)
    CONSUME(pb0, qb0, 8)  CONSUME(pb1, qb1, 9)  CONSUME(pb2, qb2, 10) CONSUME(pb3, qb3, 11)
    CONSUME(pb4, qb4, 12) CONSUME(pb5, qb5, 13) CONSUME(pb6, qb6, 14) CONSUME(pb7, qb7, 15)
    FLUSH
#undef CONSUME
#undef FLUSH
}

// ================= fin: meanH = XL2acc/deg -> bf16 into XL2 cols [40,296) ====================
__global__ __launch_bounds__(256) void fin(const float* __restrict__ XL2acc,
                                           const int* __restrict__ cnt,
                                           __hip_bfloat16* __restrict__ XL2) {
    int tid = threadIdx.x;
    int n = blockIdx.x * 4 + (tid >> 6);
    int lane = tid & 63;
    if (n < NN) {
        f32x4 a = *(const f32x4*)&XL2acc[(size_t)n * 256 + lane * 4];
        float inv = 1.f / fmaxf((float)cnt[n], 1.f);
        short4v ov;
#pragma unroll
        for (int i = 0; i < 4; ++i) ov[i] = (short)ftou16(a[i] * inv);
        *(short4v*)&XL2[(size_t)n * K2 + 40 + lane * 4] = ov;
    }
}

// ================= gemm2 + LayerNorm + ReLU + pool, fully fused =================
__global__ __launch_bounds__(256, 2) void gemm2_lnp(const u16* __restrict__ A, const u16* __restrict__ Bt,
                                                    const int* __restrict__ cnt, const int* __restrict__ batch,
                                                    const float* __restrict__ bn, const float* __restrict__ crow,
                                                    const float* __restrict__ gamma, const float* __restrict__ beta,
                                                    const float* __restrict__ ginv, float* __restrict__ out) {
    __shared__ __align__(16) u16 At[64 * 64];
    __shared__ __align__(16) u16 Bs[256 * 64];
    __shared__ float rsum[4][64], rsum2[4][64];
    __shared__ int sdeg[64], sbatch[64];
    int tid = threadIdx.x;
    long m0 = (long)blockIdx.x * 64;
    int w = tid >> 6, lane = tid & 63;
    int quad = lane >> 4, l16 = lane & 15;
    f32x4 acc[4][4] = {};
    int r0 = tid >> 3;
    int cc = (tid & 7) * 8;
    const u16* Ab = A + (m0 + r0) * K2 + cc;
    const u16* Bb = Bt + (long)r0 * K2 + cc;
    for (int kt = 0; kt < K2; kt += 64) {
#pragma unroll
        for (int i = 0; i < 2; ++i) {
            int row = r0 + i * 32;
            __builtin_amdgcn_global_load_lds(
                (const __attribute__((address_space(1))) void*)(Ab + (long)(i * 32) * K2 + kt),
                (__attribute__((address_space(3))) void*)(&At[row * 64 + cc]), 16, 0, 0);
        }
#pragma unroll
        for (int i = 0; i < 8; ++i) {
            int row = r0 + i * 32;
            __builtin_amdgcn_global_load_lds(
                (const __attribute__((address_space(1))) void*)(Bb + (long)(i * 32) * K2 + kt),
                (__attribute__((address_space(3))) void*)(&Bs[row * 64 + cc]), 16, 0, 0);
        }
        __syncthreads();
#pragma unroll
        for (int kk = 0; kk < 64; kk += 32) {
            short8 af[4], bf[4];
#pragma unroll
            for (int mi = 0; mi < 4; ++mi)
                af[mi] = *(const short8*)&At[(mi * 16 + l16) * 64 + kk + quad * 8];
#pragma unroll
            for (int ni = 0; ni < 4; ++ni)
                bf[ni] = *(const short8*)&Bs[(w * 64 + ni * 16 + l16) * 64 + kk + quad * 8];
#pragma unroll
            for (int mi = 0; mi < 4; ++mi) {
#pragma unroll
                for (int ni = 0; ni < 4; ++ni)
                    acc[mi][ni] = __builtin_amdgcn_mfma_f32_16x16x32_bf16(af[mi], bf[ni], acc[mi][ni], 0, 0, 0);
            }
        }
        __syncthreads();
    }
    if (tid < 64) {
        long n = m0 + tid;
        sdeg[tid] = (n < NN) ? cnt[n] : 0;
        sbatch[tid] = (n < NN) ? batch[n] : -1;
    }
    __syncthreads();
    float bn_l[4], cr_l[4], g_l[4], be_l[4];
#pragma unroll
    for (int ni = 0; ni < 4; ++ni) {
        int col = w * 64 + ni * 16 + l16;
        bn_l[ni] = bn[col];
        cr_l[ni] = crow[col];
        g_l[ni] = gamma[col];
        be_l[ni] = beta[col];
    }
#pragma unroll
    for (int mi = 0; mi < 4; ++mi) {
#pragma unroll
        for (int r = 0; r < 4; ++r) {
            int row = mi * 16 + quad * 4 + r;
            float cr_on = (sdeg[row] > 0) ? 1.f : 0.f;
            float s = 0.f, s2 = 0.f;
#pragma unroll
            for (int ni = 0; ni < 4; ++ni) {
                float xv = acc[mi][ni][r] + bn_l[ni] + cr_on * cr_l[ni];
                acc[mi][ni][r] = xv;
                s += xv;
                s2 += xv * xv;
            }
            s += __shfl_xor(s, 1, 64);  s2 += __shfl_xor(s2, 1, 64);
            s += __shfl_xor(s, 2, 64);  s2 += __shfl_xor(s2, 2, 64);
            s += __shfl_xor(s, 4, 64);  s2 += __shfl_xor(s2, 4, 64);
            s += __shfl_xor(s, 8, 64);  s2 += __shfl_xor(s2, 8, 64);
            if (l16 == 0) { rsum[w][row] = s; rsum2[w][row] = s2; }
        }
    }
    __syncthreads();
    float mu_a[4][4], rs_a[4][4];
#pragma unroll
    for (int mi = 0; mi < 4; ++mi) {
#pragma unroll
        for (int r = 0; r < 4; ++r) {
            int row = mi * 16 + quad * 4 + r;
            float S = rsum[0][row] + rsum[1][row] + rsum[2][row] + rsum[3][row];
            float S2 = rsum2[0][row] + rsum2[1][row] + rsum2[2][row] + rsum2[3][row];
            float mu = S * (1.f / 256.f);
            mu_a[mi][r] = mu;
            rs_a[mi][r] = rsqrtf(S2 * (1.f / 256.f) - mu * mu + 1e-5f);
        }
    }
#pragma unroll
    for (int ni = 0; ni < 4; ++ni) {
        int col = w * 64 + ni * 16 + l16;
        float pacc = 0.f;
        int curg = -1;
#pragma unroll
    for (int mi = 0; mi < 4; ++mi) {
#pragma unroll
            for (int r = 0; r < 4; ++r) {
                int row = mi * 16 + quad * 4 + r;
                int g = sbatch[row];
                float y = (acc[mi][ni][r] - mu_a[mi][r]) * rs_a[mi][r] * g_l[ni] + be_l[ni];
                y = fmaxf(y, 0.f);
                if (g != curg) {
                    if (curg >= 0) atomicAdd(&out[curg * 256 + col], pacc * ginv[curg]);
                    pacc = 0.f;
                    curg = g;
                }
                if (g >= 0) pacc += y;
            }
        }
        if (curg >= 0) atomicAdd(&out[curg * 256 + col], pacc * ginv[curg]);
    }
}

extern "C" void kernel_launch(void* const* d_in, const int* in_sizes, int n_in,
                              void* d_out, int out_size, void* d_ws, size_t ws_size,
                              hipStream_t stream) {
    const float* node_s = (const float*)d_in[0];
    const float* node_v = (const float*)d_in[1];
    const float* edge_s = (const float*)d_in[2];
    const int* ei = (const int*)d_in[3];
    const int* batch = (const int*)d_in[4];
    const float* Ws = (const float*)d_in[5];
    const float* bs = (const float*)d_in[6];
    const float* Wv = (const float*)d_in[7];
    const float* bv = (const float*)d_in[8];
    const float* We = (const float*)d_in[9];
    const float* be = (const float*)d_in[10];
    const float* Wm1 = (const float*)d_in[11];
    const float* bm1 = (const float*)d_in[12];
    const float* Wm2 = (const float*)d_in[13];
    const float* bm2 = (const float*)d_in[14];
    const float* Wn = (const float*)d_in[15];
    const float* bn = (const float*)d_in[16];
    const float* gamma = (const float*)d_in[17];
    const float* beta = (const float*)d_in[18];

    char* ws = (char*)d_ws;
    size_t off = 0;
    auto take = [&](size_t n) {
        void* p = ws + off;
        off = (off + n + 255) & ~(size_t)255;
        return p;
    };
    __hip_bfloat16* XL2 = (__hip_bfloat16*)take((size_t)MP * K2 * 2);
    __hip_bfloat16* PQ = (__hip_bfloat16*)take((size_t)MP * 512 * 2);
    __hip_bfloat16* W1pqT = (__hip_bfloat16*)take(512 * KS * 2);
    __hip_bfloat16* W2T = (__hip_bfloat16*)take(256 * K2 * 2);
    float* Wc = (float*)take(17 * 256 * 4);
    float* bc = (float*)take(256 * 4);
    float* crow = (float*)take(256 * 4);
    u16* WcBf = (u16*)take(16 * 512 * 2);
    float* XL2acc = (float*)take((size_t)NN * 256 * 4);   // 51.2 MB float accumulator
    int* cnt = (int*)take(NN * 4);
    int* gstart = (int*)take((GG + 1) * 4);
    float* ginv = (float*)take(GG * 4);
    int* rowptr = (int*)take((NN + 1) * 4);
    int* cursor = (int*)take(NN * 4);
    int* eid = (int*)take(EE * 4);
    int* bsum = (int*)take(256 * 4);

    hipMemsetAsync(cnt, 0, NN * 4, stream);
    hipMemsetAsync(d_out, 0, (size_t)out_size * 4, stream);

    phase1<<<14662 + ZB, 256, 0, stream>>>(Wm1, Wn, Wm2, We, be, bm1, bm2, Ws, bs,
                                           W1pqT, W2T, Wc, bc, crow,
                                           node_s, node_v, Wv, bv, XL2, ei, batch, cnt, gstart,
                                           XL2acc);

    scan1<<<196, 256, 0, stream>>>(cnt, rowptr, bsum);
    scan2<<<1, 256, 0, stream>>>(bsum, gstart, ginv);
    scan3<<<196, 256, 0, stream>>>(cnt, bsum, rowptr, cursor);

    // fused: gemm1 (PQ = XL2[:, :64] @ W1pqT^T) + fill_csr + WcBf pack
    gemm1_fill<<<3128, 256, 0, stream>>>((const u16*)XL2, (const u16*)W1pqT, PQ, ei, cursor, eid,
                                         Wc, WcBf);

    // edge-centric aggregation: 1 wave per 16-edge CSR group, atomic flush into XL2acc
    edge_agg<<<NG / 4, 256, 0, stream>>>((const u16*)PQ, edge_s, ei, eid, WcBf, bc, XL2acc);

    // meanH -> bf16 into XL2 cols [40,296)
    fin<<<12500, 256, 0, stream>>>(XL2acc, cnt, XL2);

    // fused: h = XL2 @ W2T^T -> LN -> ReLU -> mean-pool into d_out
    gemm2_lnp<<<782, 256, 0, stream>>>((const u16*)XL2, (const u16*)W2T, cnt, batch,
                                       bn, crow, gamma, beta, ginv, (float*)d_out);
}

// Round 7
// 309.418 us; speedup vs baseline: 1.6214x; 1.6214x over previous
//
#include <hip/hip_runtime.h>
#include <hip/hip_bf16.h>

typedef unsigned short u16;
typedef __attribute__((ext_vector_type(8))) short short8;
typedef __attribute__((ext_vector_type(4))) short short4v;
typedef __attribute__((ext_vector_type(4))) float f32x4;

#define NN 50000
#define EE 400000
#define GG 256
#define MP 50048      // 391 * 128 padded rows
#define KS 64         // gemm1 K: 23 node_s + 16 vnorm + 1 ones + 24 zero
#define K2 320        // gemm2 K: 40 + 256 meanH + 24 zero
#define EWS 260       // u16 stride for EW LDS rows (4q*130 = 8q mod 32 -> conflict-free scatter)

static __device__ __forceinline__ __hip_bfloat16 f2b(float x) { return __float2bfloat16(x); }
static __device__ __forceinline__ float u16tof(u16 v) {
    unsigned x = ((unsigned)v) << 16;
    float f;
    __builtin_memcpy(&f, &x, 4);
    return f;
}
static __device__ __forceinline__ u16 ftou16(float x) {
    __hip_bfloat16 h = __float2bfloat16(x);
    u16 b;
    __builtin_memcpy(&b, &h, 2);
    return b;
}

// uniform row a[j] (scalar loads) dotted with column b[j*256+c] (coalesced).
static __device__ __forceinline__ float dot256(const float* __restrict__ a,
                                               const float* __restrict__ b, int c) {
    const float* __restrict__ bp = b + c;
    float s0 = 0.f, s1 = 0.f, s2 = 0.f, s3 = 0.f;
    float s4 = 0.f, s5 = 0.f, s6 = 0.f, s7 = 0.f;
#pragma unroll 4
    for (int j = 0; j < 256; j += 8) {
        s0 += a[j]     * bp[(size_t)(j)     * 256];
        s1 += a[j + 1] * bp[(size_t)(j + 1) * 256];
        s2 += a[j + 2] * bp[(size_t)(j + 2) * 256];
        s3 += a[j + 3] * bp[(size_t)(j + 3) * 256];
        s4 += a[j + 4] * bp[(size_t)(j + 4) * 256];
        s5 += a[j + 5] * bp[(size_t)(j + 5) * 256];
        s6 += a[j + 6] * bp[(size_t)(j + 6) * 256];
        s7 += a[j + 7] * bp[(size_t)(j + 7) * 256];
    }
    return ((s0 + s1) + (s2 + s3)) + ((s4 + s5) + (s6 + s7));
}

// ================= phase1: weight packing + embed-lite + degree counts + batch boundaries ======
__global__ __launch_bounds__(256) void phase1(const float* __restrict__ Wm1,
                                              const float* __restrict__ Wn,
                                              const float* __restrict__ Wm2,
                                              const float* __restrict__ We,
                                              const float* __restrict__ be,
                                              const float* __restrict__ bm1,
                                              const float* __restrict__ bm2,
                                              const float* __restrict__ Ws,
                                              const float* __restrict__ bs,
                                              __hip_bfloat16* __restrict__ W1pqT,
                                              __hip_bfloat16* __restrict__ W2T,
                                              float* __restrict__ Wc, float* __restrict__ bc,
                                              float* __restrict__ crow,
                                              const float* __restrict__ node_s,
                                              const float* __restrict__ node_v,
                                              const float* __restrict__ Wv,
                                              const float* __restrict__ bv,
                                              __hip_bfloat16* __restrict__ XL2,
                                              const int* __restrict__ ei,
                                              const int* __restrict__ batch,
                                              int* __restrict__ cnt,
                                              int* __restrict__ gstart) {
    int blk = blockIdx.x, tid = threadIdx.x;
    if (blk < 64) {
        int k = blk;
#pragma unroll
        for (int half = 0; half < 2; ++half) {
            int c = half * 256 + tid;
            int cc = c & 255;
            const float* Wm1h = (c < 256) ? Wm1 : (Wm1 + 256 * 256);
            float v = 0.f;
            if (k < 23) v = dot256(&Ws[k * 256], Wm1h, cc);
            else if (k < 39) { if (c >= 256) v = Wm1[(512 + (k - 23)) * 256 + cc]; }
            else if (k == 39) v = dot256(bs, Wm1h, cc);
            W1pqT[c * KS + k] = f2b(v);
        }
    } else if (blk < 384) {
        int k = blk - 64, c = tid;
        float v = 0.f;
        if (k < 23) v = dot256(&Ws[k * 256], Wn, c);
        else if (k < 39) v = Wn[(256 + (k - 23)) * 256 + c];
        else if (k == 39) v = dot256(bs, Wn, c);
        else if (k < 296) v = dot256(&Wm2[(k - 40) * 256], Wn, c);
        W2T[c * K2 + k] = f2b(v);
    } else if (blk < 403) {
        int b = blk - 384, c = tid;
        if (b < 17) Wc[b * 256 + c] = dot256(&We[b * 256], &Wm1[528 * 256], c);
        else if (b == 17) bc[c] = bm1[c] + dot256(be, &Wm1[528 * 256], c);
        else crow[c] = dot256(bm2, Wn, c);
    } else if (blk < 12903) {
        int w = tid >> 6, lane = tid & 63;
        int n = (blk - 403) * 4 + w;
        if (n < NN) {
            float lv = (lane < 23) ? node_s[(size_t)n * 23 + lane] : 0.f;
            float vv = (lane < 12) ? node_v[(size_t)n * 12 + lane] : 0.f;
            float nvk[12];
#pragma unroll
            for (int k = 0; k < 12; ++k) nvk[k] = __shfl(vv, k, 64);
            float vn = 0.f;
            if (lane < 16) {
                float b0 = bv[lane];
                float vx = b0, vy = b0, vz = b0;
#pragma unroll
                for (int k = 0; k < 4; ++k) {
                    float wv = Wv[k * 16 + lane];
                    vx += nvk[k * 3 + 0] * wv;
                    vy += nvk[k * 3 + 1] * wv;
                    vz += nvk[k * 3 + 2] * wv;
                }
                vn = sqrtf(vx * vx + vy * vy + vz * vz);
            }
            int vsrc = (lane >= 23 && lane < 39) ? (lane - 23) : 0;
            float vbc = __shfl(vn, vsrc, 64);
            float outv;
            if (lane < 23) outv = lv;
            else if (lane < 39) outv = vbc;
            else if (lane == 39) outv = 1.f;
            else outv = 0.f;
            __hip_bfloat16* row = XL2 + (size_t)n * K2;
            row[lane] = f2b(outv);
            if (lane < 24) row[296 + lane] = f2b(0.f);
        }
    } else if (blk < 14466) {
        int e = (blk - 12903) * 256 + tid;
        if (e < EE) atomicAdd(&cnt[ei[EE + e]], 1);
    } else {
        // sorted batch -> gstart[g] = lower_bound(g); covers g in [0,GG] exactly once.
        int n = (blk - 14466) * 256 + tid;
        if (n < NN) {
            int bn = batch[n];
            int bp = (n == 0) ? -1 : batch[n - 1];
            for (int g = bp + 1; g <= bn; ++g) gstart[g] = n;
            if (n == NN - 1)
                for (int g = bn + 1; g <= GG; ++g) gstart[g] = NN;
        }
    }
}

// ================= CSR build =================
__global__ __launch_bounds__(256) void scan1(const int* __restrict__ cnt, int* __restrict__ rowptr,
                                             int* __restrict__ bsum) {
    int tid = threadIdx.x, i = blockIdx.x * 256 + tid;
    __shared__ int sd[256];
    int v = (i < NN) ? cnt[i] : 0;
    sd[tid] = v;
    __syncthreads();
    for (int off = 1; off < 256; off <<= 1) {
        int t = (tid >= off) ? sd[tid - off] : 0;
        __syncthreads();
        sd[tid] += t;
        __syncthreads();
    }
    if (i < NN) rowptr[i] = sd[tid] - v;
    if (tid == 255) bsum[blockIdx.x] = sd[255];
}
__global__ __launch_bounds__(256) void scan2(int* __restrict__ bsum, const int* __restrict__ gstart,
                                             float* __restrict__ ginv) {
    int c = threadIdx.x;
    __shared__ int sd[256];
    int v = (c < 196) ? bsum[c] : 0;
    sd[c] = v;
    __syncthreads();
    for (int off = 1; off < 256; off <<= 1) {
        int t = (c >= off) ? sd[c - off] : 0;
        __syncthreads();
        sd[c] += t;
        __syncthreads();
    }
    if (c < 196) bsum[c] = sd[c] - v;
    ginv[c] = 1.f / fmaxf((float)(gstart[c + 1] - gstart[c]), 1.f);
}
__global__ __launch_bounds__(256) void scan3(const int* __restrict__ cnt, const int* __restrict__ bsum,
                                             int* __restrict__ rowptr, int* __restrict__ cursor) {
    int i = blockIdx.x * 256 + threadIdx.x;
    if (i < NN) {
        int v = rowptr[i] + bsum[blockIdx.x];
        rowptr[i] = v;
        cursor[i] = v;
        if (i == NN - 1) rowptr[NN] = v + cnt[i];
    }
}

// ================= gemm1 + fill_csr(+srcv) + WcBf pack, fused (independent jobs) =============
// blocks [0,1564): gemm1 tile; [1564,3127): fill_csr; 3127: pack Wc into MFMA B-fragments
__global__ __launch_bounds__(256, 2) void gemm1_fill(const u16* __restrict__ A, const u16* __restrict__ Bt,
                                                     __hip_bfloat16* __restrict__ C,
                                                     const int* __restrict__ ei, int* __restrict__ cursor,
                                                     int* __restrict__ eid, int* __restrict__ srcv,
                                                     const float* __restrict__ Wc,
                                                     u16* __restrict__ WcBf) {
    __shared__ __align__(16) u16 At[128 * 64];
    __shared__ __align__(16) u16 Bs[128 * 64];
    int blk = blockIdx.x, tid = threadIdx.x;
    if (blk >= 1564) {
        if (blk == 3127) {
            // WcBf[ni*512 + l*8 + j] = bf16(Wc[k][ni*16 + (l&15)]), k=(l>>4)*8+j, 0 if k>=17
            for (int idx = tid; idx < 8192; idx += 256) {
                int ni = idx >> 9;
                int l = (idx >> 3) & 63;
                int j = idx & 7;
                int k = ((l >> 4) << 3) + j;
                int c = ni * 16 + (l & 15);
                float v = (k < 17) ? Wc[k * 256 + c] : 0.f;
                WcBf[idx] = ftou16(v);
            }
            return;
        }
        int e = (blk - 1564) * 256 + tid;
        if (e < EE) {
            int d = ei[EE + e];
            int s = ei[e];
            int pos = atomicAdd(&cursor[d], 1);
            eid[pos] = e;
            srcv[pos] = s;
        }
        return;
    }
    long m0 = (long)(blk >> 2) * 128;
    long n0 = (long)(blk & 3) * 128;
    int wid = tid >> 6, lane = tid & 63;
    int wm = wid >> 1, wn = wid & 1;
    int quad = lane >> 4, l16 = lane & 15;
    f32x4 acc[4][4] = {};
    int r0 = tid >> 3;
    int cc = (tid & 7) * 8;
    const u16* Ab = A + (m0 + r0) * K2 + cc;
    const u16* Bb = Bt + (n0 + r0) * KS + cc;
#pragma unroll
    for (int i = 0; i < 4; ++i) {
        int row = r0 + i * 32;
        __builtin_amdgcn_global_load_lds(
            (const __attribute__((address_space(1))) void*)(Ab + (long)(i * 32) * K2),
            (__attribute__((address_space(3))) void*)(&At[row * 64 + cc]), 16, 0, 0);
    }
#pragma unroll
    for (int i = 0; i < 4; ++i) {
        int row = r0 + i * 32;
        __builtin_amdgcn_global_load_lds(
            (const __attribute__((address_space(1))) void*)(Bb + (long)(i * 32) * KS),
            (__attribute__((address_space(3))) void*)(&Bs[row * 64 + cc]), 16, 0, 0);
    }
    __syncthreads();
#pragma unroll
    for (int kk = 0; kk < 64; kk += 32) {
        short8 af[4], bf[4];
#pragma unroll
        for (int mi = 0; mi < 4; ++mi)
            af[mi] = *(const short8*)&At[(wm * 64 + mi * 16 + l16) * 64 + kk + quad * 8];
#pragma unroll
        for (int ni = 0; ni < 4; ++ni)
            bf[ni] = *(const short8*)&Bs[(wn * 64 + ni * 16 + l16) * 64 + kk + quad * 8];
#pragma unroll
        for (int mi = 0; mi < 4; ++mi) {
#pragma unroll
            for (int ni = 0; ni < 4; ++ni)
                acc[mi][ni] = __builtin_amdgcn_mfma_f32_16x16x32_bf16(af[mi], bf[ni], acc[mi][ni], 0, 0, 0);
        }
    }
#pragma unroll
    for (int mi = 0; mi < 4; ++mi) {
#pragma unroll
        for (int ni = 0; ni < 4; ++ni) {
            long row = m0 + wm * 64 + mi * 16 + quad * 4;
            long col = n0 + wn * 64 + ni * 16 + l16;
#pragma unroll
            for (int r = 0; r < 4; ++r)
                C[(row + r) * 512 + col] = f2b(acc[mi][ni][r]);
        }
    }
}

// ================= edge aggregation: 2 waves/block (1 node/wave), MFMA es@Wc, ==============
// ================= parallel srcv/eid loads, full-group 16-deep Q prefetch ==================
// hidden_e = relu(P[dst]+bc + Q[src] + es[e]@Wc); meanH -> XL2 cols [40,296).
__global__ __launch_bounds__(128) void edge_agg(const u16* __restrict__ PQ,
                                                const float* __restrict__ edge_s,
                                                const int* __restrict__ srcv,
                                                const int* __restrict__ eid,
                                                const int* __restrict__ rowptr,
                                                const u16* __restrict__ WcBf,
                                                const float* __restrict__ bc,
                                                __hip_bfloat16* __restrict__ XL2) {
    __shared__ __align__(16) u16 EWall[2][16 * EWS];
    int tid = threadIdx.x;
    int wv = tid >> 6, lane = tid & 63;
    int n = blockIdx.x * 2 + wv;
    if (n >= NN) return;
    u16* __restrict__ EW = &EWall[wv][0];
    int start = rowptr[n], deg = rowptr[n + 1] - start;
    int l16 = lane & 15, quad = lane >> 4;
    // persistent Wc B-fragments (16 dim-chunks x bf16x8)
    short8 wcf[16];
#pragma unroll
    for (int ni = 0; ni < 16; ++ni)
        wcf[ni] = *(const short8*)&WcBf[ni * 512 + lane * 8];
    f32x4 bc4 = *(const f32x4*)&bc[lane * 4];
    short4v p4 = *(const short4v*)&PQ[(size_t)n * 512 + lane * 4];
    f32x4 pb;
#pragma unroll
    for (int i = 0; i < 4; ++i) pb[i] = u16tof((u16)p4[i]) + bc4[i];
    f32x4 acc = {0.f, 0.f, 0.f, 0.f};
    const f32x4 zf = {0.f, 0.f, 0.f, 0.f};
    for (int base = 0; base < deg; base += 64) {
        int m = deg - base;
        if (m > 64) m = 64;
        int mm1 = m - 1;
        int ee = 0, ss = 0;
        if (lane < m) {
            ee = eid[start + base + lane];   // for es gather only
            ss = srcv[start + base + lane];  // src ids: independent load, no ei hop
        }
        // wave-uniform Q gather by chunk position p (clamped -> dup loads hit L1)
        auto loadQ = [&](int p) {
            int pc = (p < mm1) ? p : mm1;
            int s = __builtin_amdgcn_readlane(ss, pc);
            return *(const short4v*)&PQ[(size_t)s * 512 + 256 + lane * 4];
        };
        int ng = (m + 15) >> 4;
        for (int g = 0; g < ng; ++g) {
            int b16 = g * 16;
            // ---- batch A: issue Q loads for edges 0..7 of this group ----
            short4v qA0 = loadQ(b16 + 0);
            short4v qA1 = loadQ(b16 + 1);
            short4v qA2 = loadQ(b16 + 2);
            short4v qA3 = loadQ(b16 + 3);
            short4v qA4 = loadQ(b16 + 4);
            short4v qA5 = loadQ(b16 + 5);
            short4v qA6 = loadQ(b16 + 6);
            short4v qA7 = loadQ(b16 + 7);
            // ---- build A fragment: 16 edges' es rows, K=32 (zero past 17), clamped idx ----
            int li = b16 + l16;
            if (li > mm1) li = mm1;
            int ev = __shfl(ee, li, 64);
            const float* ep = edge_s + (size_t)ev * 17 + quad * 8;
            float a0 = 0.f, a1 = 0.f, a2 = 0.f, a3 = 0.f, a4 = 0.f, a5 = 0.f, a6 = 0.f, a7 = 0.f;
            if (quad < 2) {
                a0 = ep[0]; a1 = ep[1]; a2 = ep[2]; a3 = ep[3];
                a4 = ep[4]; a5 = ep[5]; a6 = ep[6]; a7 = ep[7];
            } else if (quad == 2) {
                a0 = ep[0];
            }
            short8 af;
            af[0] = (short)ftou16(a0); af[1] = (short)ftou16(a1);
            af[2] = (short)ftou16(a2); af[3] = (short)ftou16(a3);
            af[4] = (short)ftou16(a4); af[5] = (short)ftou16(a5);
            af[6] = (short)ftou16(a6); af[7] = (short)ftou16(a7);
            // ---- 16 MFMA (one per 16-dim chunk) + conflict-free LDS scatter ----
#pragma unroll
            for (int ni = 0; ni < 16; ++ni) {
                f32x4 ew = __builtin_amdgcn_mfma_f32_16x16x32_bf16(af, wcf[ni], zf, 0, 0, 0);
#pragma unroll
                for (int r = 0; r < 4; ++r)
                    EW[(quad * 4 + r) * EWS + ni * 16 + l16] = ftou16(ew[r]);
            }
            // ---- batch B: issue Q loads for edges 8..15 ----
            short4v qB0 = loadQ(b16 + 8);
            short4v qB1 = loadQ(b16 + 9);
            short4v qB2 = loadQ(b16 + 10);
            short4v qB3 = loadQ(b16 + 11);
            short4v qB4 = loadQ(b16 + 12);
            short4v qB5 = loadQ(b16 + 13);
            short4v qB6 = loadQ(b16 + 14);
            short4v qB7 = loadQ(b16 + 15);
            int mg = m - b16;
            if (mg > 16) mg = 16;
#define CONSUME(QQ, c)                                                              \
            {                                                                       \
                int jj = (c);                                                       \
                if (jj < mg) {                                                      \
                    short4v ew4 = *(const short4v*)&EW[jj * EWS + lane * 4];        \
                    _Pragma("unroll")                                               \
                    for (int i = 0; i < 4; ++i)                                     \
                        acc[i] += fmaxf(pb[i] + u16tof((u16)QQ[i]) +                \
                                        u16tof((u16)ew4[i]), 0.f);                  \
                }                                                                   \
            }
            CONSUME(qA0, 0)  CONSUME(qA1, 1)  CONSUME(qA2, 2)  CONSUME(qA3, 3)
            CONSUME(qA4, 4)  CONSUME(qA5, 5)  CONSUME(qA6, 6)  CONSUME(qA7, 7)
            CONSUME(qB0, 8)  CONSUME(qB1, 9)  CONSUME(qB2, 10) CONSUME(qB3, 11)
            CONSUME(qB4, 12) CONSUME(qB5, 13) CONSUME(qB6, 14) CONSUME(qB7, 15)
#undef CONSUME
        }
    }
    float inv = 1.f / fmaxf((float)deg, 1.f);
    short4v ov;
#pragma unroll
    for (int i = 0; i < 4; ++i) ov[i] = (short)ftou16(acc[i] * inv);
    *(short4v*)&XL2[(size_t)n * K2 + 40 + lane * 4] = ov;
}

// ================= gemm2 + LayerNorm + ReLU + pool, fully fused =================
__global__ __launch_bounds__(256, 2) void gemm2_lnp(const u16* __restrict__ A, const u16* __restrict__ Bt,
                                                    const int* __restrict__ cnt, const int* __restrict__ batch,
                                                    const float* __restrict__ bn, const float* __restrict__ crow,
                                                    const float* __restrict__ gamma, const float* __restrict__ beta,
                                                    const float* __restrict__ ginv, float* __restrict__ out) {
    __shared__ __align__(16) u16 At[64 * 64];
    __shared__ __align__(16) u16 Bs[256 * 64];
    __shared__ float rsum[4][64], rsum2[4][64];
    __shared__ int sdeg[64], sbatch[64];
    int tid = threadIdx.x;
    long m0 = (long)blockIdx.x * 64;
    int w = tid >> 6, lane = tid & 63;
    int quad = lane >> 4, l16 = lane & 15;
    f32x4 acc[4][4] = {};
    int r0 = tid >> 3;
    int cc = (tid & 7) * 8;
    const u16* Ab = A + (m0 + r0) * K2 + cc;
    const u16* Bb = Bt + (long)r0 * K2 + cc;
    for (int kt = 0; kt < K2; kt += 64) {
#pragma unroll
        for (int i = 0; i < 2; ++i) {
            int row = r0 + i * 32;
            __builtin_amdgcn_global_load_lds(
                (const __attribute__((address_space(1))) void*)(Ab + (long)(i * 32) * K2 + kt),
                (__attribute__((address_space(3))) void*)(&At[row * 64 + cc]), 16, 0, 0);
        }
#pragma unroll
        for (int i = 0; i < 8; ++i) {
            int row = r0 + i * 32;
            __builtin_amdgcn_global_load_lds(
                (const __attribute__((address_space(1))) void*)(Bb + (long)(i * 32) * K2 + kt),
                (__attribute__((address_space(3))) void*)(&Bs[row * 64 + cc]), 16, 0, 0);
        }
        __syncthreads();
#pragma unroll
        for (int kk = 0; kk < 64; kk += 32) {
            short8 af[4], bf[4];
#pragma unroll
            for (int mi = 0; mi < 4; ++mi)
                af[mi] = *(const short8*)&At[(mi * 16 + l16) * 64 + kk + quad * 8];
#pragma unroll
            for (int ni = 0; ni < 4; ++ni)
                bf[ni] = *(const short8*)&Bs[(w * 64 + ni * 16 + l16) * 64 + kk + quad * 8];
#pragma unroll
            for (int mi = 0; mi < 4; ++mi) {
#pragma unroll
                for (int ni = 0; ni < 4; ++ni)
                    acc[mi][ni] = __builtin_amdgcn_mfma_f32_16x16x32_bf16(af[mi], bf[ni], acc[mi][ni], 0, 0, 0);
            }
        }
        __syncthreads();
    }
    if (tid < 64) {
        long n = m0 + tid;
        sdeg[tid] = (n < NN) ? cnt[n] : 0;
        sbatch[tid] = (n < NN) ? batch[n] : -1;
    }
    __syncthreads();
    float bn_l[4], cr_l[4], g_l[4], be_l[4];
#pragma unroll
    for (int ni = 0; ni < 4; ++ni) {
        int col = w * 64 + ni * 16 + l16;
        bn_l[ni] = bn[col];
        cr_l[ni] = crow[col];
        g_l[ni] = gamma[col];
        be_l[ni] = beta[col];
    }
#pragma unroll
    for (int mi = 0; mi < 4; ++mi) {
#pragma unroll
        for (int r = 0; r < 4; ++r) {
            int row = mi * 16 + quad * 4 + r;
            float cr_on = (sdeg[row] > 0) ? 1.f : 0.f;
            float s = 0.f, s2 = 0.f;
#pragma unroll
            for (int ni = 0; ni < 4; ++ni) {
                float xv = acc[mi][ni][r] + bn_l[ni] + cr_on * cr_l[ni];
                acc[mi][ni][r] = xv;
                s += xv;
                s2 += xv * xv;
            }
            s += __shfl_xor(s, 1, 64);  s2 += __shfl_xor(s2, 1, 64);
            s += __shfl_xor(s, 2, 64);  s2 += __shfl_xor(s2, 2, 64);
            s += __shfl_xor(s, 4, 64);  s2 += __shfl_xor(s2, 4, 64);
            s += __shfl_xor(s, 8, 64);  s2 += __shfl_xor(s2, 8, 64);
            if (l16 == 0) { rsum[w][row] = s; rsum2[w][row] = s2; }
        }
    }
    __syncthreads();
    float mu_a[4][4], rs_a[4][4];
#pragma unroll
    for (int mi = 0; mi < 4; ++mi) {
#pragma unroll
        for (int r = 0; r < 4; ++r) {
            int row = mi * 16 + quad * 4 + r;
            float S = rsum[0][row] + rsum[1][row] + rsum[2][row] + rsum[3][row];
            float S2 = rsum2[0][row] + rsum2[1][row] + rsum2[2][row] + rsum2[3][row];
            float mu = S * (1.f / 256.f);
            mu_a[mi][r] = mu;
            rs_a[mi][r] = rsqrtf(S2 * (1.f / 256.f) - mu * mu + 1e-5f);
        }
    }
#pragma unroll
    for (int ni = 0; ni < 4; ++ni) {
        int col = w * 64 + ni * 16 + l16;
        float pacc = 0.f;
        int curg = -1;
#pragma unroll
        for (int mi = 0; mi < 4; ++mi) {
#pragma unroll
            for (int r = 0; r < 4; ++r) {
                int row = mi * 16 + quad * 4 + r;
                int g = sbatch[row];
                float y = (acc[mi][ni][r] - mu_a[mi][r]) * rs_a[mi][r] * g_l[ni] + be_l[ni];
                y = fmaxf(y, 0.f);
                if (g != curg) {
                    if (curg >= 0) atomicAdd(&out[curg * 256 + col], pacc * ginv[curg]);
                    pacc = 0.f;
                    curg = g;
                }
                if (g >= 0) pacc += y;
            }
        }
        if (curg >= 0) atomicAdd(&out[curg * 256 + col], pacc * ginv[curg]);
    }
}

extern "C" void kernel_launch(void* const* d_in, const int* in_sizes, int n_in,
                              void* d_out, int out_size, void* d_ws, size_t ws_size,
                              hipStream_t stream) {
    const float* node_s = (const float*)d_in[0];
    const float* node_v = (const float*)d_in[1];
    const float* edge_s = (const float*)d_in[2];
    const int* ei = (const int*)d_in[3];
    const int* batch = (const int*)d_in[4];
    const float* Ws = (const float*)d_in[5];
    const float* bs = (const float*)d_in[6];
    const float* Wv = (const float*)d_in[7];
    const float* bv = (const float*)d_in[8];
    const float* We = (const float*)d_in[9];
    const float* be = (const float*)d_in[10];
    const float* Wm1 = (const float*)d_in[11];
    const float* bm1 = (const float*)d_in[12];
    const float* Wm2 = (const float*)d_in[13];
    const float* bm2 = (const float*)d_in[14];
    const float* Wn = (const float*)d_in[15];
    const float* bn = (const float*)d_in[16];
    const float* gamma = (const float*)d_in[17];
    const float* beta = (const float*)d_in[18];

    char* ws = (char*)d_ws;
    size_t off = 0;
    auto take = [&](size_t n) {
        void* p = ws + off;
        off = (off + n + 255) & ~(size_t)255;
        return p;
    };
    __hip_bfloat16* XL2 = (__hip_bfloat16*)take((size_t)MP * K2 * 2);
    __hip_bfloat16* PQ = (__hip_bfloat16*)take((size_t)MP * 512 * 2);
    __hip_bfloat16* W1pqT = (__hip_bfloat16*)take(512 * KS * 2);
    __hip_bfloat16* W2T = (__hip_bfloat16*)take(256 * K2 * 2);
    float* Wc = (float*)take(17 * 256 * 4);
    float* bc = (float*)take(256 * 4);
    float* crow = (float*)take(256 * 4);
    u16* WcBf = (u16*)take(16 * 512 * 2);
    int* cnt = (int*)take(NN * 4);
    int* gstart = (int*)take((GG + 1) * 4);
    float* ginv = (float*)take(GG * 4);
    int* rowptr = (int*)take((NN + 1) * 4);
    int* cursor = (int*)take(NN * 4);
    int* eid = (int*)take(EE * 4);
    int* srcv = (int*)take(EE * 4);
    int* bsum = (int*)take(256 * 4);

    hipMemsetAsync(cnt, 0, NN * 4, stream);
    hipMemsetAsync(d_out, 0, (size_t)out_size * 4, stream);

    phase1<<<14662, 256, 0, stream>>>(Wm1, Wn, Wm2, We, be, bm1, bm2, Ws, bs,
                                      W1pqT, W2T, Wc, bc, crow,
                                      node_s, node_v, Wv, bv, XL2, ei, batch, cnt, gstart);

    scan1<<<196, 256, 0, stream>>>(cnt, rowptr, bsum);
    scan2<<<1, 256, 0, stream>>>(bsum, gstart, ginv);
    scan3<<<196, 256, 0, stream>>>(cnt, bsum, rowptr, cursor);

    // fused: gemm1 (PQ = XL2[:, :64] @ W1pqT^T) + fill_csr(+srcv) + WcBf pack
    gemm1_fill<<<3128, 256, 0, stream>>>((const u16*)XL2, (const u16*)W1pqT, PQ, ei, cursor, eid,
                                         srcv, Wc, WcBf);

    // node-centric aggregation: 2 waves/block, 1 node/wave
    edge_agg<<<25000, 128, 0, stream>>>((const u16*)PQ, edge_s, srcv, eid, rowptr, WcBf, bc, XL2);

    // fused: h = XL2 @ W2T^T -> LN -> ReLU -> mean-pool into d_out
    gemm2_lnp<<<782, 256, 0, stream>>>((const u16*)XL2, (const u16*)W2T, cnt, batch,
                                       bn, crow, gamma, beta, ginv, (float*)d_out);
}

// Round 9
// 290.961 us; speedup vs baseline: 1.7242x; 1.0634x over previous
//
#include <hip/hip_runtime.h>
#include <hip/hip_bf16.h>

typedef unsigned short u16;
typedef __attribute__((ext_vector_type(8))) short short8;
typedef __attribute__((ext_vector_type(4))) short short4v;
typedef __attribute__((ext_vector_type(4))) float f32x4;

#define NN 50000
#define EE 400000
#define GG 256
#define MP 50048      // 391 * 128 padded rows
#define KS 64         // gemm1 K: 23 node_s + 16 vnorm + 1 ones + 24 zero
#define K2 320        // gemm2 K: 40 + 256 meanH + 24 zero
#define EWS 260       // u16 stride for EW LDS rows (4q*130 = 8q mod 32 -> conflict-free scatter)

static __device__ __forceinline__ __hip_bfloat16 f2b(float x) { return __float2bfloat16(x); }
static __device__ __forceinline__ float u16tof(u16 v) {
    unsigned x = ((unsigned)v) << 16;
    float f;
    __builtin_memcpy(&f, &x, 4);
    return f;
}
static __device__ __forceinline__ u16 ftou16(float x) {
    __hip_bfloat16 h = __float2bfloat16(x);
    u16 b;
    __builtin_memcpy(&b, &h, 2);
    return b;
}

// uniform row a[j] (scalar loads) dotted with column b[j*256+c] (coalesced).
static __device__ __forceinline__ float dot256(const float* __restrict__ a,
                                               const float* __restrict__ b, int c) {
    const float* __restrict__ bp = b + c;
    float s0 = 0.f, s1 = 0.f, s2 = 0.f, s3 = 0.f;
    float s4 = 0.f, s5 = 0.f, s6 = 0.f, s7 = 0.f;
#pragma unroll 4
    for (int j = 0; j < 256; j += 8) {
        s0 += a[j]     * bp[(size_t)(j)     * 256];
        s1 += a[j + 1] * bp[(size_t)(j + 1) * 256];
        s2 += a[j + 2] * bp[(size_t)(j + 2) * 256];
        s3 += a[j + 3] * bp[(size_t)(j + 3) * 256];
        s4 += a[j + 4] * bp[(size_t)(j + 4) * 256];
        s5 += a[j + 5] * bp[(size_t)(j + 5) * 256];
        s6 += a[j + 6] * bp[(size_t)(j + 6) * 256];
        s7 += a[j + 7] * bp[(size_t)(j + 7) * 256];
    }
    return ((s0 + s1) + (s2 + s3)) + ((s4 + s5) + (s6 + s7));
}

// ================= phase1: weight packing + embed-lite + degree counts + batch boundaries ======
// [0,64) W1pqT dot256 | [64,74) W2T via MFMA (10 tile blocks, no LDS) | [74,93) Wc/bc/crow
// [93,12593) embed | [12593,14156) deg counts | [14156,14352) batch bounds
__global__ __launch_bounds__(256) void phase1(const float* __restrict__ Wm1,
                                              const float* __restrict__ Wn,
                                              const float* __restrict__ Wm2,
                                              const float* __restrict__ We,
                                              const float* __restrict__ be,
                                              const float* __restrict__ bm1,
                                              const float* __restrict__ bm2,
                                              const float* __restrict__ Ws,
                                              const float* __restrict__ bs,
                                              __hip_bfloat16* __restrict__ W1pqT,
                                              __hip_bfloat16* __restrict__ W2T,
                                              float* __restrict__ Wc, float* __restrict__ bc,
                                              float* __restrict__ crow,
                                              const float* __restrict__ node_s,
                                              const float* __restrict__ node_v,
                                              const float* __restrict__ Wv,
                                              const float* __restrict__ bv,
                                              __hip_bfloat16* __restrict__ XL2,
                                              const int* __restrict__ ei,
                                              const int* __restrict__ batch,
                                              int* __restrict__ cnt,
                                              int* __restrict__ gstart) {
    int blk = blockIdx.x, tid = threadIdx.x;
    if (blk < 64) {
        int k = blk;
#pragma unroll
        for (int half = 0; half < 2; ++half) {
            int c = half * 256 + tid;
            int cc = c & 255;
            const float* Wm1h = (c < 256) ? Wm1 : (Wm1 + 256 * 256);
            float v = 0.f;
            if (k < 23) v = dot256(&Ws[k * 256], Wm1h, cc);
            else if (k < 39) { if (c >= 256) v = Wm1[(512 + (k - 23)) * 256 + cc]; }
            else if (k == 39) v = dot256(bs, Wm1h, cc);
            W1pqT[c * KS + k] = f2b(v);
        }
    } else if (blk < 74) {
        // ---- W2T[c][k] = sum_j A[k][j] * Wn[j][c] via MFMA; A = [Ws;0;bs;Wm2;0] (320x256) ----
        // 10 blocks: 5 k-tiles (64) x 2 c-tiles (128). Fragments loaded direct from global f32.
        int wb = blk - 64;
        int kt0 = (wb >> 1) * 64;
        int c0 = (wb & 1) * 128;
        int w = tid >> 6, lane = tid & 63;
        int quad = lane >> 4, l16 = lane & 15;
        f32x4 acc[4][2] = {};
        for (int jt = 0; jt < 256; jt += 32) {
            int j0 = jt + quad * 8;
            short8 af[4], bf[2];
#pragma unroll
            for (int mi = 0; mi < 4; ++mi) {
                int k = kt0 + mi * 16 + l16;
                const float* ar = nullptr;
                if (k < 23) ar = Ws + (size_t)k * 256;
                else if (k == 39) ar = bs;
                else if (k >= 40 && k < 296) ar = Wm2 + (size_t)(k - 40) * 256;
                float v0 = 0.f, v1 = 0.f, v2 = 0.f, v3 = 0.f, v4 = 0.f, v5 = 0.f, v6 = 0.f, v7 = 0.f;
                if (ar) {
                    f32x4 x0 = *(const f32x4*)(ar + j0);
                    f32x4 x1 = *(const f32x4*)(ar + j0 + 4);
                    v0 = x0[0]; v1 = x0[1]; v2 = x0[2]; v3 = x0[3];
                    v4 = x1[0]; v5 = x1[1]; v6 = x1[2]; v7 = x1[3];
                }
                af[mi][0] = (short)ftou16(v0); af[mi][1] = (short)ftou16(v1);
                af[mi][2] = (short)ftou16(v2); af[mi][3] = (short)ftou16(v3);
                af[mi][4] = (short)ftou16(v4); af[mi][5] = (short)ftou16(v5);
                af[mi][6] = (short)ftou16(v6); af[mi][7] = (short)ftou16(v7);
            }
#pragma unroll
            for (int ni = 0; ni < 2; ++ni) {
                int c = c0 + w * 32 + ni * 16 + l16;
#pragma unroll
                for (int u = 0; u < 8; ++u)
                    bf[ni][u] = (short)ftou16(Wn[(size_t)(j0 + u) * 256 + c]);
            }
#pragma unroll
            for (int mi = 0; mi < 4; ++mi) {
#pragma unroll
                for (int ni = 0; ni < 2; ++ni)
                    acc[mi][ni] = __builtin_amdgcn_mfma_f32_16x16x32_bf16(af[mi], bf[ni], acc[mi][ni], 0, 0, 0);
            }
        }
#pragma unroll
        for (int mi = 0; mi < 4; ++mi) {
#pragma unroll
            for (int ni = 0; ni < 2; ++ni) {
                int c = c0 + w * 32 + ni * 16 + l16;
#pragma unroll
                for (int r = 0; r < 4; ++r) {
                    int k = kt0 + mi * 16 + quad * 4 + r;
                    float v = acc[mi][ni][r];
                    if (k >= 23 && k < 39) v = Wn[(size_t)(256 + k - 23) * 256 + c];
                    W2T[(size_t)c * K2 + k] = f2b(v);
                }
            }
        }
    } else if (blk < 93) {
        int b = blk - 74, c = tid;
        if (b < 17) Wc[b * 256 + c] = dot256(&We[b * 256], &Wm1[528 * 256], c);
        else if (b == 17) bc[c] = bm1[c] + dot256(be, &Wm1[528 * 256], c);
        else crow[c] = dot256(bm2, Wn, c);
    } else if (blk < 12593) {
        int w = tid >> 6, lane = tid & 63;
        int n = (blk - 93) * 4 + w;
        if (n < NN) {
            float lv = (lane < 23) ? node_s[(size_t)n * 23 + lane] : 0.f;
            float vv = (lane < 12) ? node_v[(size_t)n * 12 + lane] : 0.f;
            float nvk[12];
#pragma unroll
            for (int k = 0; k < 12; ++k) nvk[k] = __shfl(vv, k, 64);
            float vn = 0.f;
            if (lane < 16) {
                float b0 = bv[lane];
                float vx = b0, vy = b0, vz = b0;
#pragma unroll
                for (int k = 0; k < 4; ++k) {
                    float wv = Wv[k * 16 + lane];
                    vx += nvk[k * 3 + 0] * wv;
                    vy += nvk[k * 3 + 1] * wv;
                    vz += nvk[k * 3 + 2] * wv;
                }
                vn = sqrtf(vx * vx + vy * vy + vz * vz);
            }
            int vsrc = (lane >= 23 && lane < 39) ? (lane - 23) : 0;
            float vbc = __shfl(vn, vsrc, 64);
            float outv;
            if (lane < 23) outv = lv;
            else if (lane < 39) outv = vbc;
            else if (lane == 39) outv = 1.f;
            else outv = 0.f;
            __hip_bfloat16* row = XL2 + (size_t)n * K2;
            row[lane] = f2b(outv);
            if (lane < 24) row[296 + lane] = f2b(0.f);
        }
    } else if (blk < 14156) {
        int e = (blk - 12593) * 256 + tid;
        if (e < EE) atomicAdd(&cnt[ei[EE + e]], 1);
    } else {
        // sorted batch -> gstart[g] = lower_bound(g); covers g in [0,GG] exactly once.
        int n = (blk - 14156) * 256 + tid;
        if (n < NN) {
            int bn = batch[n];
            int bp = (n == 0) ? -1 : batch[n - 1];
            for (int g = bp + 1; g <= bn; ++g) gstart[g] = n;
            if (n == NN - 1)
                for (int g = bn + 1; g <= GG; ++g) gstart[g] = NN;
        }
    }
}

// ================= CSR build =================
__global__ __launch_bounds__(256) void scan1(const int* __restrict__ cnt, int* __restrict__ rowptr,
                                             int* __restrict__ bsum) {
    int tid = threadIdx.x, i = blockIdx.x * 256 + tid;
    __shared__ int sd[256];
    int v = (i < NN) ? cnt[i] : 0;
    sd[tid] = v;
    __syncthreads();
    for (int off = 1; off < 256; off <<= 1) {
        int t = (tid >= off) ? sd[tid - off] : 0;
        __syncthreads();
        sd[tid] += t;
        __syncthreads();
    }
    if (i < NN) rowptr[i] = sd[tid] - v;
    if (tid == 255) bsum[blockIdx.x] = sd[255];
}
__global__ __launch_bounds__(256) void scan2(int* __restrict__ bsum, const int* __restrict__ gstart,
                                             float* __restrict__ ginv) {
    int c = threadIdx.x;
    __shared__ int sd[256];
    int v = (c < 196) ? bsum[c] : 0;
    sd[c] = v;
    __syncthreads();
    for (int off = 1; off < 256; off <<= 1) {
        int t = (c >= off) ? sd[c - off] : 0;
        __syncthreads();
        sd[c] += t;
        __syncthreads();
    }
    if (c < 196) bsum[c] = sd[c] - v;
    ginv[c] = 1.f / fmaxf((float)(gstart[c + 1] - gstart[c]), 1.f);
}
__global__ __launch_bounds__(256) void scan3(const int* __restrict__ cnt, const int* __restrict__ bsum,
                                             int* __restrict__ rowptr, int* __restrict__ cursor) {
    int i = blockIdx.x * 256 + threadIdx.x;
    if (i < NN) {
        int v = rowptr[i] + bsum[blockIdx.x];
        rowptr[i] = v;
        cursor[i] = v;
        if (i == NN - 1) rowptr[NN] = v + cnt[i];
    }
}

// ================= gemm1 + fill_csr(+srcv) + WcBf pack, fused (independent jobs) =============
// blocks [0,1564): gemm1 tile; [1564,3127): fill_csr; 3127: pack Wc into MFMA B-fragments
__global__ __launch_bounds__(256, 2) void gemm1_fill(const u16* __restrict__ A, const u16* __restrict__ Bt,
                                                     __hip_bfloat16* __restrict__ C,
                                                     const int* __restrict__ ei, int* __restrict__ cursor,
                                                     int* __restrict__ eid, int* __restrict__ srcv,
                                                     const float* __restrict__ Wc,
                                                     u16* __restrict__ WcBf) {
    __shared__ __align__(16) u16 At[128 * 64];
    __shared__ __align__(16) u16 Bs[128 * 64];
    int blk = blockIdx.x, tid = threadIdx.x;
    if (blk >= 1564) {
        if (blk == 3127) {
            // WcBf[ni*512 + l*8 + j] = bf16(Wc[k][ni*16 + (l&15)]), k=(l>>4)*8+j, 0 if k>=17
            for (int idx = tid; idx < 8192; idx += 256) {
                int ni = idx >> 9;
                int l = (idx >> 3) & 63;
                int j = idx & 7;
                int k = ((l >> 4) << 3) + j;
                int c = ni * 16 + (l & 15);
                float v = (k < 17) ? Wc[k * 256 + c] : 0.f;
                WcBf[idx] = ftou16(v);
            }
            return;
        }
        int e = (blk - 1564) * 256 + tid;
        if (e < EE) {
            int d = ei[EE + e];
            int s = ei[e];
            int pos = atomicAdd(&cursor[d], 1);
            eid[pos] = e;
            srcv[pos] = s;
        }
        return;
    }
    long m0 = (long)(blk >> 2) * 128;
    long n0 = (long)(blk & 3) * 128;
    int wid = tid >> 6, lane = tid & 63;
    int wm = wid >> 1, wn = wid & 1;
    int quad = lane >> 4, l16 = lane & 15;
    f32x4 acc[4][4] = {};
    int r0 = tid >> 3;
    int cc = (tid & 7) * 8;
    const u16* Ab = A + (m0 + r0) * K2 + cc;
    const u16* Bb = Bt + (n0 + r0) * KS + cc;
#pragma unroll
    for (int i = 0; i < 4; ++i) {
        int row = r0 + i * 32;
        __builtin_amdgcn_global_load_lds(
            (const __attribute__((address_space(1))) void*)(Ab + (long)(i * 32) * K2),
            (__attribute__((address_space(3))) void*)(&At[row * 64 + cc]), 16, 0, 0);
    }
#pragma unroll
    for (int i = 0; i < 4; ++i) {
        int row = r0 + i * 32;
        __builtin_amdgcn_global_load_lds(
            (const __attribute__((address_space(1))) void*)(Bb + (long)(i * 32) * KS),
            (__attribute__((address_space(3))) void*)(&Bs[row * 64 + cc]), 16, 0, 0);
    }
    __syncthreads();
#pragma unroll
    for (int kk = 0; kk < 64; kk += 32) {
        short8 af[4], bf[4];
#pragma unroll
        for (int mi = 0; mi < 4; ++mi)
            af[mi] = *(const short8*)&At[(wm * 64 + mi * 16 + l16) * 64 + kk + quad * 8];
#pragma unroll
        for (int ni = 0; ni < 4; ++ni)
            bf[ni] = *(const short8*)&Bs[(wn * 64 + ni * 16 + l16) * 64 + kk + quad * 8];
#pragma unroll
        for (int mi = 0; mi < 4; ++mi) {
#pragma unroll
            for (int ni = 0; ni < 4; ++ni)
                acc[mi][ni] = __builtin_amdgcn_mfma_f32_16x16x32_bf16(af[mi], bf[ni], acc[mi][ni], 0, 0, 0);
        }
    }
#pragma unroll
    for (int mi = 0; mi < 4; ++mi) {
#pragma unroll
        for (int ni = 0; ni < 4; ++ni) {
            long row = m0 + wm * 64 + mi * 16 + quad * 4;
            long col = n0 + wn * 64 + ni * 16 + l16;
#pragma unroll
            for (int r = 0; r < 4; ++r)
                C[(row + r) * 512 + col] = f2b(acc[mi][ni][r]);
        }
    }
}

// ================= edge aggregation: 1-wave blocks (best measured occupancy), MFMA es@Wc, ====
// ================= parallel srcv/eid loads, 16-deep Q prefetch, batch-B skip for small deg ===
// hidden_e = relu(P[dst]+bc + Q[src] + es[e]@Wc); meanH -> XL2 cols [40,296).
__global__ __launch_bounds__(64) void edge_agg(const u16* __restrict__ PQ,
                                               const float* __restrict__ edge_s,
                                               const int* __restrict__ srcv,
                                               const int* __restrict__ eid,
                                               const int* __restrict__ rowptr,
                                               const u16* __restrict__ WcBf,
                                               const float* __restrict__ bc,
                                               __hip_bfloat16* __restrict__ XL2) {
    __shared__ __align__(16) u16 EW[16 * EWS];
    int lane = threadIdx.x;
    int n = blockIdx.x;
    int start = rowptr[n], deg = rowptr[n + 1] - start;
    int l16 = lane & 15, quad = lane >> 4;
    // persistent Wc B-fragments (16 dim-chunks x bf16x8)
    short8 wcf[16];
#pragma unroll
    for (int ni = 0; ni < 16; ++ni)
        wcf[ni] = *(const short8*)&WcBf[ni * 512 + lane * 8];
    f32x4 bc4 = *(const f32x4*)&bc[lane * 4];
    short4v p4 = *(const short4v*)&PQ[(size_t)n * 512 + lane * 4];
    f32x4 pb;
#pragma unroll
    for (int i = 0; i < 4; ++i) pb[i] = u16tof((u16)p4[i]) + bc4[i];
    f32x4 acc = {0.f, 0.f, 0.f, 0.f};
    const f32x4 zf = {0.f, 0.f, 0.f, 0.f};
    for (int base = 0; base < deg; base += 64) {
        int m = deg - base;
        if (m > 64) m = 64;
        int mm1 = m - 1;
        int ee = 0, ss = 0;
        if (lane < m) {
            ee = eid[start + base + lane];   // for es gather only
            ss = srcv[start + base + lane];  // src ids: independent load, no ei hop
        }
        // wave-uniform Q gather by chunk position p (clamped -> dup loads hit L1)
        auto loadQ = [&](int p) {
            int pc = (p < mm1) ? p : mm1;
            int s = __builtin_amdgcn_readlane(ss, pc);
            return *(const short4v*)&PQ[(size_t)s * 512 + 256 + lane * 4];
        };
        int ng = (m + 15) >> 4;
        for (int g = 0; g < ng; ++g) {
            int b16 = g * 16;
            // ---- batch A: issue Q loads for edges 0..7 of this group ----
            short4v qA0 = loadQ(b16 + 0);
            short4v qA1 = loadQ(b16 + 1);
            short4v qA2 = loadQ(b16 + 2);
            short4v qA3 = loadQ(b16 + 3);
            short4v qA4 = loadQ(b16 + 4);
            short4v qA5 = loadQ(b16 + 5);
            short4v qA6 = loadQ(b16 + 6);
            short4v qA7 = loadQ(b16 + 7);
            // ---- build A fragment: 16 edges' es rows, K=32 (zero past 17), clamped idx ----
            int li = b16 + l16;
            if (li > mm1) li = mm1;
            int ev = __shfl(ee, li, 64);
            const float* ep = edge_s + (size_t)ev * 17 + quad * 8;
            float a0 = 0.f, a1 = 0.f, a2 = 0.f, a3 = 0.f, a4 = 0.f, a5 = 0.f, a6 = 0.f, a7 = 0.f;
            if (quad < 2) {
                a0 = ep[0]; a1 = ep[1]; a2 = ep[2]; a3 = ep[3];
                a4 = ep[4]; a5 = ep[5]; a6 = ep[6]; a7 = ep[7];
            } else if (quad == 2) {
                a0 = ep[0];
            }
            short8 af;
            af[0] = (short)ftou16(a0); af[1] = (short)ftou16(a1);
            af[2] = (short)ftou16(a2); af[3] = (short)ftou16(a3);
            af[4] = (short)ftou16(a4); af[5] = (short)ftou16(a5);
            af[6] = (short)ftou16(a6); af[7] = (short)ftou16(a7);
            // ---- 16 MFMA (one per 16-dim chunk) + conflict-free LDS scatter ----
#pragma unroll
            for (int ni = 0; ni < 16; ++ni) {
                f32x4 ew = __builtin_amdgcn_mfma_f32_16x16x32_bf16(af, wcf[ni], zf, 0, 0, 0);
#pragma unroll
                for (int r = 0; r < 4; ++r)
                    EW[(quad * 4 + r) * EWS + ni * 16 + l16] = ftou16(ew[r]);
            }
            int mg = m - b16;
            if (mg > 16) mg = 16;
            // ---- batch B: issue Q loads for edges 8..15 only if needed (wave-uniform) ----
            short4v qB0 = {0, 0, 0, 0}, qB1 = {0, 0, 0, 0}, qB2 = {0, 0, 0, 0}, qB3 = {0, 0, 0, 0};
            short4v qB4 = {0, 0, 0, 0}, qB5 = {0, 0, 0, 0}, qB6 = {0, 0, 0, 0}, qB7 = {0, 0, 0, 0};
            if (mg > 8) {
                qB0 = loadQ(b16 + 8);
                qB1 = loadQ(b16 + 9);
                qB2 = loadQ(b16 + 10);
                qB3 = loadQ(b16 + 11);
                qB4 = loadQ(b16 + 12);
                qB5 = loadQ(b16 + 13);
                qB6 = loadQ(b16 + 14);
                qB7 = loadQ(b16 + 15);
            }
#define CONSUME(QQ, c)                                                              \
            {                                                                       \
                int jj = (c);                                                       \
                if (jj < mg) {                                                      \
                    short4v ew4 = *(const short4v*)&EW[jj * EWS + lane * 4];        \
                    _Pragma("unroll")                                               \
                    for (int i = 0; i < 4; ++i)                                     \
                        acc[i] += fmaxf(pb[i] + u16tof((u16)QQ[i]) +                \
                                        u16tof((u16)ew4[i]), 0.f);                  \
                }                                                                   \
            }
            CONSUME(qA0, 0)  CONSUME(qA1, 1)  CONSUME(qA2, 2)  CONSUME(qA3, 3)
            CONSUME(qA4, 4)  CONSUME(qA5, 5)  CONSUME(qA6, 6)  CONSUME(qA7, 7)
            CONSUME(qB0, 8)  CONSUME(qB1, 9)  CONSUME(qB2, 10) CONSUME(qB3, 11)
            CONSUME(qB4, 12) CONSUME(qB5, 13) CONSUME(qB6, 14) CONSUME(qB7, 15)
#undef CONSUME
        }
    }
    float inv = 1.f / fmaxf((float)deg, 1.f);
    short4v ov;
#pragma unroll
    for (int i = 0; i < 4; ++i) ov[i] = (short)ftou16(acc[i] * inv);
    *(short4v*)&XL2[(size_t)n * K2 + 40 + lane * 4] = ov;
}

// ================= gemm2 + LayerNorm + ReLU + pool, fully fused =================
__global__ __launch_bounds__(256, 2) void gemm2_lnp(const u16* __restrict__ A, const u16* __restrict__ Bt,
                                                    const int* __restrict__ cnt, const int* __restrict__ batch,
                                                    const float* __restrict__ bn, const float* __restrict__ crow,
                                                    const float* __restrict__ gamma, const float* __restrict__ beta,
                                                    const float* __restrict__ ginv, float* __restrict__ out) {
    __shared__ __align__(16) u16 At[64 * 64];
    __shared__ __align__(16) u16 Bs[256 * 64];
    __shared__ float rsum[4][64], rsum2[4][64];
    __shared__ int sdeg[64], sbatch[64];
    int tid = threadIdx.x;
    long m0 = (long)blockIdx.x * 64;
    int w = tid >> 6, lane = tid & 63;
    int quad = lane >> 4, l16 = lane & 15;
    f32x4 acc[4][4] = {};
    int r0 = tid >> 3;
    int cc = (tid & 7) * 8;
    const u16* Ab = A + (m0 + r0) * K2 + cc;
    const u16* Bb = Bt + (long)r0 * K2 + cc;
    for (int kt = 0; kt < K2; kt += 64) {
#pragma unroll
        for (int i = 0; i < 2; ++i) {
            int row = r0 + i * 32;
            __builtin_amdgcn_global_load_lds(
                (const __attribute__((address_space(1))) void*)(Ab + (long)(i * 32) * K2 + kt),
                (__attribute__((address_space(3))) void*)(&At[row * 64 + cc]), 16, 0, 0);
        }
#pragma unroll
        for (int i = 0; i < 8; ++i) {
            int row = r0 + i * 32;
            __builtin_amdgcn_global_load_lds(
                (const __attribute__((address_space(1))) void*)(Bb + (long)(i * 32) * K2 + kt),
                (__attribute__((address_space(3))) void*)(&Bs[row * 64 + cc]), 16, 0, 0);
        }
        __syncthreads();
#pragma unroll
        for (int kk = 0; kk < 64; kk += 32) {
            short8 af[4], bf[4];
#pragma unroll
            for (int mi = 0; mi < 4; ++mi)
                af[mi] = *(const short8*)&At[(mi * 16 + l16) * 64 + kk + quad * 8];
#pragma unroll
            for (int ni = 0; ni < 4; ++ni)
                bf[ni] = *(const short8*)&Bs[(w * 64 + ni * 16 + l16) * 64 + kk + quad * 8];
#pragma unroll
            for (int mi = 0; mi < 4; ++mi) {
#pragma unroll
                for (int ni = 0; ni < 4; ++ni)
                    acc[mi][ni] = __builtin_amdgcn_mfma_f32_16x16x32_bf16(af[mi], bf[ni], acc[mi][ni], 0, 0, 0);
            }
        }
        __syncthreads();
    }
    if (tid < 64) {
        long n = m0 + tid;
        sdeg[tid] = (n < NN) ? cnt[n] : 0;
        sbatch[tid] = (n < NN) ? batch[n] : -1;
    }
    __syncthreads();
    float bn_l[4], cr_l[4], g_l[4], be_l[4];
#pragma unroll
    for (int ni = 0; ni < 4; ++ni) {
        int col = w * 64 + ni * 16 + l16;
        bn_l[ni] = bn[col];
        cr_l[ni] = crow[col];
        g_l[ni] = gamma[col];
        be_l[ni] = beta[col];
    }
#pragma unroll
    for (int mi = 0; mi < 4; ++mi) {
#pragma unroll
        for (int r = 0; r < 4; ++r) {
            int row = mi * 16 + quad * 4 + r;
            float cr_on = (sdeg[row] > 0) ? 1.f : 0.f;
            float s = 0.f, s2 = 0.f;
#pragma unroll
            for (int ni = 0; ni < 4; ++ni) {
                float xv = acc[mi][ni][r] + bn_l[ni] + cr_on * cr_l[ni];
                acc[mi][ni][r] = xv;
                s += xv;
                s2 += xv * xv;
            }
            s += __shfl_xor(s, 1, 64);  s2 += __shfl_xor(s2, 1, 64);
            s += __shfl_xor(s, 2, 64);  s2 += __shfl_xor(s2, 2, 64);
            s += __shfl_xor(s, 4, 64);  s2 += __shfl_xor(s2, 4, 64);
            s += __shfl_xor(s, 8, 64);  s2 += __shfl_xor(s2, 8, 64);
            if (l16 == 0) { rsum[w][row] = s; rsum2[w][row] = s2; }
        }
    }
    __syncthreads();
    float mu_a[4][4], rs_a[4][4];
#pragma unroll
    for (int mi = 0; mi < 4; ++mi) {
#pragma unroll
        for (int r = 0; r < 4; ++r) {
            int row = mi * 16 + quad * 4 + r;
            float S = rsum[0][row] + rsum[1][row] + rsum[2][row] + rsum[3][row];
            float S2 = rsum2[0][row] + rsum2[1][row] + rsum2[2][row] + rsum2[3][row];
            float mu = S * (1.f / 256.f);
            mu_a[mi][r] = mu;
            rs_a[mi][r] = rsqrtf(S2 * (1.f / 256.f) - mu * mu + 1e-5f);
        }
    }
#pragma unroll
    for (int ni = 0; ni < 4; ++ni) {
        int col = w * 64 + ni * 16 + l16;
        float pacc = 0.f;
        int curg = -1;
#pragma unroll
        for (int mi = 0; mi < 4; ++mi) {
#pragma unroll
            for (int r = 0; r < 4; ++r) {
                int row = mi * 16 + quad * 4 + r;
                int g = sbatch[row];
                float y = (acc[mi][ni][r] - mu_a[mi][r]) * rs_a[mi][r] * g_l[ni] + be_l[ni];
                y = fmaxf(y, 0.f);
                if (g != curg) {
                    if (curg >= 0) atomicAdd(&out[curg * 256 + col], pacc * ginv[curg]);
                    pacc = 0.f;
                    curg = g;
                }
                if (g >= 0) pacc += y;
            }
        }
        if (curg >= 0) atomicAdd(&out[curg * 256 + col], pacc * ginv[curg]);
    }
}

extern "C" void kernel_launch(void* const* d_in, const int* in_sizes, int n_in,
                              void* d_out, int out_size, void* d_ws, size_t ws_size,
                              hipStream_t stream) {
    const float* node_s = (const float*)d_in[0];
    const float* node_v = (const float*)d_in[1];
    const float* edge_s = (const float*)d_in[2];
    const int* ei = (const int*)d_in[3];
    const int* batch = (const int*)d_in[4];
    const float* Ws = (const float*)d_in[5];
    const float* bs = (const float*)d_in[6];
    const float* Wv = (const float*)d_in[7];
    const float* bv = (const float*)d_in[8];
    const float* We = (const float*)d_in[9];
    const float* be = (const float*)d_in[10];
    const float* Wm1 = (const float*)d_in[11];
    const float* bm1 = (const float*)d_in[12];
    const float* Wm2 = (const float*)d_in[13];
    const float* bm2 = (const float*)d_in[14];
    const float* Wn = (const float*)d_in[15];
    const float* bn = (const float*)d_in[16];
    const float* gamma = (const float*)d_in[17];
    const float* beta = (const float*)d_in[18];

    char* ws = (char*)d_ws;
    size_t off = 0;
    auto take = [&](size_t n) {
        void* p = ws + off;
        off = (off + n + 255) & ~(size_t)255;
        return p;
    };
    __hip_bfloat16* XL2 = (__hip_bfloat16*)take((size_t)MP * K2 * 2);
    __hip_bfloat16* PQ = (__hip_bfloat16*)take((size_t)MP * 512 * 2);
    __hip_bfloat16* W1pqT = (__hip_bfloat16*)take(512 * KS * 2);
    __hip_bfloat16* W2T = (__hip_bfloat16*)take(256 * K2 * 2);
    float* Wc = (float*)take(17 * 256 * 4);
    float* bc = (float*)take(256 * 4);
    float* crow = (float*)take(256 * 4);
    u16* WcBf = (u16*)take(16 * 512 * 2);
    int* cnt = (int*)take(NN * 4);
    int* gstart = (int*)take((GG + 1) * 4);
    float* ginv = (float*)take(GG * 4);
    int* rowptr = (int*)take((NN + 1) * 4);
    int* cursor = (int*)take(NN * 4);
    int* eid = (int*)take(EE * 4);
    int* srcv = (int*)take(EE * 4);
    int* bsum = (int*)take(256 * 4);

    hipMemsetAsync(cnt, 0, NN * 4, stream);
    hipMemsetAsync(d_out, 0, (size_t)out_size * 4, stream);

    phase1<<<14352, 256, 0, stream>>>(Wm1, Wn, Wm2, We, be, bm1, bm2, Ws, bs,
                                      W1pqT, W2T, Wc, bc, crow,
                                      node_s, node_v, Wv, bv, XL2, ei, batch, cnt, gstart);

    scan1<<<196, 256, 0, stream>>>(cnt, rowptr, bsum);
    scan2<<<1, 256, 0, stream>>>(bsum, gstart, ginv);
    scan3<<<196, 256, 0, stream>>>(cnt, bsum, rowptr, cursor);

    // fused: gemm1 (PQ = XL2[:, :64] @ W1pqT^T) + fill_csr(+srcv) + WcBf pack
    gemm1_fill<<<3128, 256, 0, stream>>>((const u16*)XL2, (const u16*)W1pqT, PQ, ei, cursor, eid,
                                         srcv, Wc, WcBf);

    // node-centric aggregation: 1-wave blocks (best measured occupancy)
    edge_agg<<<NN, 64, 0, stream>>>((const u16*)PQ, edge_s, srcv, eid, rowptr, WcBf, bc, XL2);

    // fused: h = XL2 @ W2T^T -> LN -> ReLU -> mean-pool into d_out
    gemm2_lnp<<<782, 256, 0, stream>>>((const u16*)XL2, (const u16*)W2T, cnt, batch,
                                       bn, crow, gamma, beta, ginv, (float*)d_out);
}